// Round 1
// baseline (478.131 us; speedup 1.0000x reference)
//
#include <hip/hip_runtime.h>
#include <stdint.h>

typedef __bf16 bf16x8_t __attribute__((ext_vector_type(8)));
typedef float f32x4_t __attribute__((ext_vector_type(4)));

__device__ __forceinline__ uint32_t f32_to_bf16_bits(float f) {
    union { float f; uint32_t u; } v; v.f = f;
    // round-to-nearest-even; inputs are finite
    return (v.u + 0x7FFFu + ((v.u >> 16) & 1u)) >> 16;
}

// ---------------------------------------------------------------------------
// A[i,j] = cos(pi * j * (2i+1) / 8192), stored bf16 row-major 4096x4096.
// Exact reduction: angle index r = (j*(2i+1)) mod 16384, ang = r*pi/8192.
// 2M threads, 8 elements each (one 16B store).
// ---------------------------------------------------------------------------
__global__ void genA_kernel(unsigned short* __restrict__ A) {
    const int idx = blockIdx.x * 256 + threadIdx.x;       // 0 .. 2M-1
    const int n   = idx >> 9;                             // row 0..4095
    const int q0  = (idx & 511) << 3;                     // col start
    const uint32_t tn = (uint32_t)(2 * n + 1);
    uint32_t packed[4];
#pragma unroll
    for (int jj = 0; jj < 4; ++jj) {
        uint32_t r0 = ((uint32_t)(q0 + 2 * jj)     * tn) & 16383u;
        uint32_t r1 = ((uint32_t)(q0 + 2 * jj + 1) * tn) & 16383u;
        float c0 = __cosf((float)r0 * 3.8349519697141e-4f);  // pi/8192
        float c1 = __cosf((float)r1 * 3.8349519697141e-4f);
        packed[jj] = f32_to_bf16_bits(c0) | (f32_to_bf16_bits(c1) << 16);
    }
    ((uint4*)A)[idx] = make_uint4(packed[0], packed[1], packed[2], packed[3]);
}

// ---------------------------------------------------------------------------
// fp32 -> bf16 cast, 8 elements/thread.
// ---------------------------------------------------------------------------
__global__ void cvtX_kernel(const float* __restrict__ X, unsigned short* __restrict__ Y) {
    const int idx = blockIdx.x * 256 + threadIdx.x;       // 0 .. 2M-1
    const float4* src = (const float4*)X + (size_t)idx * 2;
    float4 a = src[0];
    float4 b = src[1];
    uint32_t p0 = f32_to_bf16_bits(a.x) | (f32_to_bf16_bits(a.y) << 16);
    uint32_t p1 = f32_to_bf16_bits(a.z) | (f32_to_bf16_bits(a.w) << 16);
    uint32_t p2 = f32_to_bf16_bits(b.x) | (f32_to_bf16_bits(b.y) << 16);
    uint32_t p3 = f32_to_bf16_bits(b.z) | (f32_to_bf16_bits(b.w) << 16);
    ((uint4*)Y)[idx] = make_uint4(p0, p1, p2, p3);
}

// ---------------------------------------------------------------------------
// C = L * R^T, all 4096x4096, L/R bf16 row-major (K contiguous).
// 128x128 block tile, BK=32, 256 threads (4 waves), each wave a 64x64
// subtile as 4x4 grid of mfma_f32_16x16x32_bf16.
// Staging: __builtin_amdgcn_global_load_lds width=16 (wave-uniform LDS base
// + lane*16; LDS layout row-major [128][32] bf16, NO padding).
// OUT_BF16=1 -> bf16 store (intermediate), 0 -> fp32 store (final).
// ---------------------------------------------------------------------------
template <int OUT_BF16>
__global__ __launch_bounds__(256)
void gemm_bt_kernel(const unsigned short* __restrict__ A,
                    const unsigned short* __restrict__ B,
                    void* __restrict__ Cout) {
    __shared__ __attribute__((aligned(16))) unsigned short lA[128 * 32];
    __shared__ __attribute__((aligned(16))) unsigned short lB[128 * 32];

    const int tid  = threadIdx.x;
    const int wave = tid >> 6;
    const int lane = tid & 63;

    const int tile_m = blockIdx.y << 7;
    const int tile_n = blockIdx.x << 7;

    f32x4_t acc[4][4];
#pragma unroll
    for (int i = 0; i < 4; ++i)
#pragma unroll
        for (int j = 0; j < 4; ++j)
            acc[i][j] = (f32x4_t){0.f, 0.f, 0.f, 0.f};

    // 512 chunks of 16B per tile: chunk c -> row c>>2, 8-elem group c&3.
    const int c_base = wave << 6;            // wave-uniform
    const int cl0 = c_base + lane;           // chunks 0..255
    const int cl1 = cl0 + 256;               // chunks 256..511

    const unsigned short* gA0 = A + (size_t)(tile_m + (cl0 >> 2)) * 4096 + ((cl0 & 3) << 3);
    const unsigned short* gA1 = A + (size_t)(tile_m + (cl1 >> 2)) * 4096 + ((cl1 & 3) << 3);
    const unsigned short* gB0 = B + (size_t)(tile_n + (cl0 >> 2)) * 4096 + ((cl0 & 3) << 3);
    const unsigned short* gB1 = B + (size_t)(tile_n + (cl1 >> 2)) * 4096 + ((cl1 & 3) << 3);

    unsigned short* lA0 = &lA[(c_base)       << 3];   // wave-uniform bases
    unsigned short* lA1 = &lA[(c_base + 256) << 3];
    unsigned short* lB0 = &lB[(c_base)       << 3];
    unsigned short* lB1 = &lB[(c_base + 256) << 3];

    // fragment addresses: A-frag lane map: m = lane&15, k = (lane>>4)*8 + j
    const int frow = lane & 15;
    const int koff = (lane >> 4) << 3;
    const unsigned short* aP = &lA[((wave >> 1) * 64 + frow) * 32 + koff];
    const unsigned short* bP = &lB[((wave & 1) * 64 + frow) * 32 + koff];

    for (int kt = 0; kt < 128; ++kt) {
        __syncthreads();   // previous tile fully consumed
        __builtin_amdgcn_global_load_lds((const __attribute__((address_space(1))) uint32_t*)gA0,
                                         (__attribute__((address_space(3))) uint32_t*)lA0, 16, 0, 0);
        __builtin_amdgcn_global_load_lds((const __attribute__((address_space(1))) uint32_t*)gA1,
                                         (__attribute__((address_space(3))) uint32_t*)lA1, 16, 0, 0);
        __builtin_amdgcn_global_load_lds((const __attribute__((address_space(1))) uint32_t*)gB0,
                                         (__attribute__((address_space(3))) uint32_t*)lB0, 16, 0, 0);
        __builtin_amdgcn_global_load_lds((const __attribute__((address_space(1))) uint32_t*)gB1,
                                         (__attribute__((address_space(3))) uint32_t*)lB1, 16, 0, 0);
        gA0 += 32; gA1 += 32; gB0 += 32; gB1 += 32;
        __syncthreads();   // staging drained (compiler emits vmcnt(0) before barrier)

        bf16x8_t af[4], bfr[4];
#pragma unroll
        for (int i = 0; i < 4; ++i) af[i]  = *(const bf16x8_t*)(aP + i * 16 * 32);
#pragma unroll
        for (int j = 0; j < 4; ++j) bfr[j] = *(const bf16x8_t*)(bP + j * 16 * 32);

#pragma unroll
        for (int i = 0; i < 4; ++i)
#pragma unroll
            for (int j = 0; j < 4; ++j)
                acc[i][j] = __builtin_amdgcn_mfma_f32_16x16x32_bf16(af[i], bfr[j], acc[i][j], 0, 0, 0);
    }

    // Epilogue. C/D map: col = lane&15, row = (lane>>4)*4 + reg  (m89/m91).
    const int orow = tile_m + (wave >> 1) * 64 + ((lane >> 4) << 2);
    const int ocol = tile_n + (wave & 1) * 64 + (lane & 15);
    if (OUT_BF16) {
        unsigned short* C = (unsigned short*)Cout;
#pragma unroll
        for (int i = 0; i < 4; ++i)
#pragma unroll
            for (int j = 0; j < 4; ++j)
#pragma unroll
                for (int r = 0; r < 4; ++r)
                    C[(size_t)(orow + i * 16 + r) * 4096 + (ocol + j * 16)] =
                        (unsigned short)f32_to_bf16_bits(acc[i][j][r]);
    } else {
        float* C = (float*)Cout;
#pragma unroll
        for (int i = 0; i < 4; ++i)
#pragma unroll
            for (int j = 0; j < 4; ++j)
#pragma unroll
                for (int r = 0; r < 4; ++r)
                    C[(size_t)(orow + i * 16 + r) * 4096 + (ocol + j * 16)] = acc[i][j][r];
    }
}

// ---------------------------------------------------------------------------
// out = A * x * A^T  as two B^T-form GEMMs:
//   t' = A * x^T   (bf16 out, ws)
//   out = A * t'^T (fp32 out, d_out)
// ws layout: A bf16 [0,32M), x bf16 [32M,64M), t' bf16 [64M,96M). Needs 96MB.
// ---------------------------------------------------------------------------
extern "C" void kernel_launch(void* const* d_in, const int* in_sizes, int n_in,
                              void* d_out, int out_size, void* d_ws, size_t ws_size,
                              hipStream_t stream) {
    const float* x = (const float*)d_in[0];
    unsigned short* Abf = (unsigned short*)d_ws;
    unsigned short* Xbf = (unsigned short*)((char*)d_ws + (size_t)32 * 1024 * 1024);
    unsigned short* Tbf = (unsigned short*)((char*)d_ws + (size_t)64 * 1024 * 1024);
    float* out = (float*)d_out;

    genA_kernel<<<8192, 256, 0, stream>>>(Abf);
    cvtX_kernel<<<8192, 256, 0, stream>>>(x, Xbf);

    dim3 grid(32, 32);
    gemm_bt_kernel<1><<<grid, 256, 0, stream>>>(Abf, Xbf, (void*)Tbf);
    gemm_bt_kernel<0><<<grid, 256, 0, stream>>>(Abf, Tbf, (void*)out);
}

// Round 2
// 326.528 us; speedup vs baseline: 1.4643x; 1.4643x over previous
//
#include <hip/hip_runtime.h>
#include <stdint.h>

typedef __bf16 bf16x8_t __attribute__((ext_vector_type(8)));
typedef float f32x4_t __attribute__((ext_vector_type(4)));

__device__ __forceinline__ uint32_t f32_to_bf16_bits(float f) {
    union { float f; uint32_t u; } v; v.f = f;
    return (v.u + 0x7FFFu + ((v.u >> 16) & 1u)) >> 16;   // RNE, finite inputs
}
__device__ __forceinline__ float bf16_bits_to_f32(uint32_t b) {
    union { uint32_t u; float f; } v; v.u = b << 16; return v.f;
}
__device__ __forceinline__ void unpack8(uint4 u, float* f) {
    f[0] = bf16_bits_to_f32(u.x & 0xffffu); f[1] = bf16_bits_to_f32(u.x >> 16);
    f[2] = bf16_bits_to_f32(u.y & 0xffffu); f[3] = bf16_bits_to_f32(u.y >> 16);
    f[4] = bf16_bits_to_f32(u.z & 0xffffu); f[5] = bf16_bits_to_f32(u.z >> 16);
    f[6] = bf16_bits_to_f32(u.w & 0xffffu); f[7] = bf16_bits_to_f32(u.w >> 16);
}

// ---------------------------------------------------------------------------
// Ae[n,r] = A[n,2r]   = cos(pi*(2r  )(2n+1)/8192)   n,r in [0,2048)
// Ao[n,r] = A[n,2r+1] = cos(pi*(2r+1)(2n+1)/8192)
// Exact angle reduction mod 16384. 1M threads, 8 elems each.
// ---------------------------------------------------------------------------
__global__ void genAB_kernel(unsigned short* __restrict__ Ae,
                             unsigned short* __restrict__ Ao) {
    const int idx = blockIdx.x * 256 + threadIdx.x;   // 0..1M-1
    const int sel = idx >> 19;                        // 0=even matrix, 1=odd
    const int e   = idx & ((1 << 19) - 1);
    const int n   = e >> 8;                           // 0..2047
    const int c0  = (e & 255) << 3;                   // col start
    const uint32_t tn = (uint32_t)(2 * n + 1);
    unsigned short* dst = sel ? Ao : Ae;
    uint32_t packed[4];
#pragma unroll
    for (int jj = 0; jj < 4; ++jj) {
        uint32_t cA = (uint32_t)(c0 + 2 * jj);
        uint32_t cB = cA + 1;
        uint32_t r0 = ((2u * cA + (uint32_t)sel) * tn) & 16383u;
        uint32_t r1 = ((2u * cB + (uint32_t)sel) * tn) & 16383u;
        float v0 = __cosf((float)r0 * 3.8349519697141e-4f);   // pi/8192
        float v1 = __cosf((float)r1 * 3.8349519697141e-4f);
        packed[jj] = f32_to_bf16_bits(v0) | (f32_to_bf16_bits(v1) << 16);
    }
    *(uint4*)(dst + (size_t)n * 2048 + c0) = make_uint4(packed[0], packed[1], packed[2], packed[3]);
}

// ---------------------------------------------------------------------------
// Deinterleave x columns: Xe[q,r]=x[q,2r], Xo[q,r]=x[q,2r+1], cast to bf16.
// ---------------------------------------------------------------------------
__global__ void cvtX_kernel(const float* __restrict__ X,
                            unsigned short* __restrict__ Xe,
                            unsigned short* __restrict__ Xo) {
    const int idx = blockIdx.x * 256 + threadIdx.x;   // 0..2M-1
    const int q   = idx >> 9;
    const int p0  = (idx & 511) << 3;
    const float4* src = (const float4*)(X + (size_t)q * 4096 + p0);
    float4 a = src[0];
    float4 b = src[1];
    uint2 ev, od;
    ev.x = f32_to_bf16_bits(a.x) | (f32_to_bf16_bits(a.z) << 16);
    ev.y = f32_to_bf16_bits(b.x) | (f32_to_bf16_bits(b.z) << 16);
    od.x = f32_to_bf16_bits(a.y) | (f32_to_bf16_bits(a.w) << 16);
    od.y = f32_to_bf16_bits(b.y) | (f32_to_bf16_bits(b.w) << 16);
    *(uint2*)(Xe + (size_t)q * 2048 + (p0 >> 1)) = ev;
    *(uint2*)(Xo + (size_t)q * 2048 + (p0 >> 1)) = od;
}

// ---------------------------------------------------------------------------
// C = L * R^T; L: 2048xK (K=2048), R: 4096xK, C: 2048x4096 bf16.
// blockIdx.z picks (Le,Re,Ce) vs (Lo,Ro,Co). 128x128 tile, BK=32,
// 4 waves x (4x4 of mfma_f32_16x16x32_bf16), global_load_lds width-16.
// ---------------------------------------------------------------------------
__global__ __launch_bounds__(256)
void gemm_bt_kernel(const unsigned short* __restrict__ Le,
                    const unsigned short* __restrict__ Lo,
                    const unsigned short* __restrict__ Re,
                    const unsigned short* __restrict__ Ro,
                    unsigned short* __restrict__ Ce,
                    unsigned short* __restrict__ Co) {
    constexpr int KD = 2048;
    __shared__ __attribute__((aligned(16))) unsigned short lA[128 * 32];
    __shared__ __attribute__((aligned(16))) unsigned short lB[128 * 32];

    const unsigned short* L = blockIdx.z ? Lo : Le;
    const unsigned short* R = blockIdx.z ? Ro : Re;
    unsigned short*       C = blockIdx.z ? Co : Ce;

    const int tid  = threadIdx.x;
    const int wave = tid >> 6;
    const int lane = tid & 63;

    const int tile_m = blockIdx.y << 7;   // 0..1920
    const int tile_n = blockIdx.x << 7;   // 0..3968

    f32x4_t acc[4][4];
#pragma unroll
    for (int i = 0; i < 4; ++i)
#pragma unroll
        for (int j = 0; j < 4; ++j)
            acc[i][j] = (f32x4_t){0.f, 0.f, 0.f, 0.f};

    const int c_base = wave << 6;
    const int cl0 = c_base + lane;
    const int cl1 = cl0 + 256;

    const unsigned short* gA0 = L + (size_t)(tile_m + (cl0 >> 2)) * KD + ((cl0 & 3) << 3);
    const unsigned short* gA1 = L + (size_t)(tile_m + (cl1 >> 2)) * KD + ((cl1 & 3) << 3);
    const unsigned short* gB0 = R + (size_t)(tile_n + (cl0 >> 2)) * KD + ((cl0 & 3) << 3);
    const unsigned short* gB1 = R + (size_t)(tile_n + (cl1 >> 2)) * KD + ((cl1 & 3) << 3);

    unsigned short* lA0 = &lA[(c_base)       << 3];
    unsigned short* lA1 = &lA[(c_base + 256) << 3];
    unsigned short* lB0 = &lB[(c_base)       << 3];
    unsigned short* lB1 = &lB[(c_base + 256) << 3];

    const int frow = lane & 15;
    const int koff = (lane >> 4) << 3;
    const unsigned short* aP = &lA[((wave >> 1) * 64 + frow) * 32 + koff];
    const unsigned short* bP = &lB[((wave & 1) * 64 + frow) * 32 + koff];

    for (int kt = 0; kt < KD / 32; ++kt) {
        __syncthreads();
        __builtin_amdgcn_global_load_lds((const __attribute__((address_space(1))) uint32_t*)gA0,
                                         (__attribute__((address_space(3))) uint32_t*)lA0, 16, 0, 0);
        __builtin_amdgcn_global_load_lds((const __attribute__((address_space(1))) uint32_t*)gA1,
                                         (__attribute__((address_space(3))) uint32_t*)lA1, 16, 0, 0);
        __builtin_amdgcn_global_load_lds((const __attribute__((address_space(1))) uint32_t*)gB0,
                                         (__attribute__((address_space(3))) uint32_t*)lB0, 16, 0, 0);
        __builtin_amdgcn_global_load_lds((const __attribute__((address_space(1))) uint32_t*)gB1,
                                         (__attribute__((address_space(3))) uint32_t*)lB1, 16, 0, 0);
        gA0 += 32; gA1 += 32; gB0 += 32; gB1 += 32;
        __syncthreads();

        bf16x8_t af[4], bfr[4];
#pragma unroll
        for (int i = 0; i < 4; ++i) af[i]  = *(const bf16x8_t*)(aP + i * 16 * 32);
#pragma unroll
        for (int j = 0; j < 4; ++j) bfr[j] = *(const bf16x8_t*)(bP + j * 16 * 32);

#pragma unroll
        for (int i = 0; i < 4; ++i)
#pragma unroll
            for (int j = 0; j < 4; ++j)
                acc[i][j] = __builtin_amdgcn_mfma_f32_16x16x32_bf16(af[i], bfr[j], acc[i][j], 0, 0, 0);
    }

    // C/D map: col = lane&15, row = (lane>>4)*4 + reg
    const int orow = tile_m + (wave >> 1) * 64 + ((lane >> 4) << 2);
    const int ocol = tile_n + (wave & 1) * 64 + (lane & 15);
#pragma unroll
    for (int i = 0; i < 4; ++i)
#pragma unroll
        for (int j = 0; j < 4; ++j)
#pragma unroll
            for (int r = 0; r < 4; ++r)
                C[(size_t)(orow + i * 16 + r) * 4096 + (ocol + j * 16)] =
                    (unsigned short)f32_to_bf16_bits(acc[i][j][r]);
}

// ---------------------------------------------------------------------------
// Butterfly 1 + column deinterleave for stage 2.
// t'[n,q]=Se+So, t'[4095-n,q]=Se-So; Te[w,r]=t'[w,2r], To[w,r]=t'[w,2r+1].
// Se,So: [2048][4096] bf16.  Te,To: [4096][2048] bf16.
// ---------------------------------------------------------------------------
__global__ void bf1_kernel(const unsigned short* __restrict__ Se,
                           const unsigned short* __restrict__ So,
                           unsigned short* __restrict__ Te,
                           unsigned short* __restrict__ To) {
    const int idx = blockIdx.x * 256 + threadIdx.x;   // 0..1M-1
    const int n   = idx >> 9;                         // 0..2047
    const int q0  = (idx & 511) << 3;
    uint4 ue = *(const uint4*)(Se + (size_t)n * 4096 + q0);
    uint4 uo = *(const uint4*)(So + (size_t)n * 4096 + q0);
    float fe[8], fo[8], s[8], d[8];
    unpack8(ue, fe); unpack8(uo, fo);
#pragma unroll
    for (int j = 0; j < 8; ++j) { s[j] = fe[j] + fo[j]; d[j] = fe[j] - fo[j]; }
    const int mir = 4095 - n;
    const int col = q0 >> 1;
    uint2 te_n, to_n, te_m, to_m;
    te_n.x = f32_to_bf16_bits(s[0]) | (f32_to_bf16_bits(s[2]) << 16);
    te_n.y = f32_to_bf16_bits(s[4]) | (f32_to_bf16_bits(s[6]) << 16);
    to_n.x = f32_to_bf16_bits(s[1]) | (f32_to_bf16_bits(s[3]) << 16);
    to_n.y = f32_to_bf16_bits(s[5]) | (f32_to_bf16_bits(s[7]) << 16);
    te_m.x = f32_to_bf16_bits(d[0]) | (f32_to_bf16_bits(d[2]) << 16);
    te_m.y = f32_to_bf16_bits(d[4]) | (f32_to_bf16_bits(d[6]) << 16);
    to_m.x = f32_to_bf16_bits(d[1]) | (f32_to_bf16_bits(d[3]) << 16);
    to_m.y = f32_to_bf16_bits(d[5]) | (f32_to_bf16_bits(d[7]) << 16);
    *(uint2*)(Te + (size_t)n   * 2048 + col) = te_n;
    *(uint2*)(To + (size_t)n   * 2048 + col) = to_n;
    *(uint2*)(Te + (size_t)mir * 2048 + col) = te_m;
    *(uint2*)(To + (size_t)mir * 2048 + col) = to_m;
}

// ---------------------------------------------------------------------------
// Butterfly 2: out[m,w]=Se2+So2 (fp32), out[4095-m,w]=Se2-So2.
// ---------------------------------------------------------------------------
__global__ void bf2_kernel(const unsigned short* __restrict__ Se,
                           const unsigned short* __restrict__ So,
                           float* __restrict__ out) {
    const int idx = blockIdx.x * 256 + threadIdx.x;   // 0..1M-1
    const int m   = idx >> 9;                         // 0..2047
    const int w0  = (idx & 511) << 3;
    uint4 ue = *(const uint4*)(Se + (size_t)m * 4096 + w0);
    uint4 uo = *(const uint4*)(So + (size_t)m * 4096 + w0);
    float fe[8], fo[8];
    unpack8(ue, fe); unpack8(uo, fo);
    float4 s0 = make_float4(fe[0] + fo[0], fe[1] + fo[1], fe[2] + fo[2], fe[3] + fo[3]);
    float4 s1 = make_float4(fe[4] + fo[4], fe[5] + fo[5], fe[6] + fo[6], fe[7] + fo[7]);
    float4 d0 = make_float4(fe[0] - fo[0], fe[1] - fo[1], fe[2] - fo[2], fe[3] - fo[3]);
    float4 d1 = make_float4(fe[4] - fo[4], fe[5] - fo[5], fe[6] - fo[6], fe[7] - fo[7]);
    float* pn = out + (size_t)m * 4096 + w0;
    float* pm = out + (size_t)(4095 - m) * 4096 + w0;
    *(float4*)(pn)     = s0;
    *(float4*)(pn + 4) = s1;
    *(float4*)(pm)     = d0;
    *(float4*)(pm + 4) = d1;
}

// ---------------------------------------------------------------------------
// Pipeline: stage1  Se=Ae*Xe^T, So=Ao*Xo^T  -> bf1 -> Te,To (aliases Xe,Xo)
//           stage2  Se2=Ae*Te^T, So2=Ao*To^T (alias Se,So) -> bf2 -> out
// ws: Ae[0,8M) Ao[8M,16M) Xe/Te[16M,32M) Xo/To[32M,48M) Se[48M,64M) So[64M,80M)
// ---------------------------------------------------------------------------
extern "C" void kernel_launch(void* const* d_in, const int* in_sizes, int n_in,
                              void* d_out, int out_size, void* d_ws, size_t ws_size,
                              hipStream_t stream) {
    const float* x = (const float*)d_in[0];
    char* ws = (char*)d_ws;
    const size_t MB = 1024 * 1024;
    unsigned short* Ae = (unsigned short*)(ws);
    unsigned short* Ao = (unsigned short*)(ws + 8 * MB);
    unsigned short* Xe = (unsigned short*)(ws + 16 * MB);
    unsigned short* Xo = (unsigned short*)(ws + 32 * MB);
    unsigned short* Se = (unsigned short*)(ws + 48 * MB);
    unsigned short* So = (unsigned short*)(ws + 64 * MB);
    unsigned short* Te = Xe;   // alias: Xe dead after stage-1 GEMM
    unsigned short* To = Xo;
    float* out = (float*)d_out;

    genAB_kernel<<<4096, 256, 0, stream>>>(Ae, Ao);
    cvtX_kernel<<<8192, 256, 0, stream>>>(x, Xe, Xo);

    dim3 grid(32, 16, 2);
    gemm_bt_kernel<<<grid, 256, 0, stream>>>(Ae, Ao, Xe, Xo, Se, So);
    bf1_kernel<<<4096, 256, 0, stream>>>(Se, So, Te, To);
    gemm_bt_kernel<<<grid, 256, 0, stream>>>(Ae, Ao, Te, To, Se, So);
    bf2_kernel<<<4096, 256, 0, stream>>>(Se, So, out);
}

// Round 3
// 300.392 us; speedup vs baseline: 1.5917x; 1.0870x over previous
//
#include <hip/hip_runtime.h>
#include <stdint.h>

typedef __bf16 bf16x8_t __attribute__((ext_vector_type(8)));
typedef float f32x4_t __attribute__((ext_vector_type(4)));

__device__ __forceinline__ uint32_t f32_to_bf16_bits(float f) {
    union { float f; uint32_t u; } v; v.f = f;
    return (v.u + 0x7FFFu + ((v.u >> 16) & 1u)) >> 16;   // RNE, finite inputs
}

// ---------------------------------------------------------------------------
// Ae[n,r] = cos(pi*(2r)(2n+1)/8192), Ao[n,r] = cos(pi*(2r+1)(2n+1)/8192),
// n,r in [0,2048). Exact angle reduction mod 16384.
// ---------------------------------------------------------------------------
__global__ void genAB_kernel(unsigned short* __restrict__ Ae,
                             unsigned short* __restrict__ Ao) {
    const int idx = blockIdx.x * 256 + threadIdx.x;   // 0..1M-1
    const int sel = idx >> 19;                        // 0=even matrix, 1=odd
    const int e   = idx & ((1 << 19) - 1);
    const int n   = e >> 8;                           // 0..2047
    const int c0  = (e & 255) << 3;                   // col start
    const uint32_t tn = (uint32_t)(2 * n + 1);
    unsigned short* dst = sel ? Ao : Ae;
    uint32_t packed[4];
#pragma unroll
    for (int jj = 0; jj < 4; ++jj) {
        uint32_t cA = (uint32_t)(c0 + 2 * jj);
        uint32_t cB = cA + 1;
        uint32_t r0 = ((2u * cA + (uint32_t)sel) * tn) & 16383u;
        uint32_t r1 = ((2u * cB + (uint32_t)sel) * tn) & 16383u;
        float v0 = __cosf((float)r0 * 3.8349519697141e-4f);   // pi/8192
        float v1 = __cosf((float)r1 * 3.8349519697141e-4f);
        packed[jj] = f32_to_bf16_bits(v0) | (f32_to_bf16_bits(v1) << 16);
    }
    *(uint4*)(dst + (size_t)n * 2048 + c0) = make_uint4(packed[0], packed[1], packed[2], packed[3]);
}

// ---------------------------------------------------------------------------
// Deinterleave x columns: Xe[q,r]=x[q,2r], Xo[q,r]=x[q,2r+1], cast to bf16.
// ---------------------------------------------------------------------------
__global__ void cvtX_kernel(const float* __restrict__ X,
                            unsigned short* __restrict__ Xe,
                            unsigned short* __restrict__ Xo) {
    const int idx = blockIdx.x * 256 + threadIdx.x;   // 0..2M-1
    const int q   = idx >> 9;
    const int p0  = (idx & 511) << 3;
    const float4* src = (const float4*)(X + (size_t)q * 4096 + p0);
    float4 a = src[0];
    float4 b = src[1];
    uint2 ev, od;
    ev.x = f32_to_bf16_bits(a.x) | (f32_to_bf16_bits(a.z) << 16);
    ev.y = f32_to_bf16_bits(b.x) | (f32_to_bf16_bits(b.z) << 16);
    od.x = f32_to_bf16_bits(a.y) | (f32_to_bf16_bits(a.w) << 16);
    od.y = f32_to_bf16_bits(b.y) | (f32_to_bf16_bits(b.w) << 16);
    *(uint2*)(Xe + (size_t)q * 2048 + (p0 >> 1)) = ev;
    *(uint2*)(Xo + (size_t)q * 2048 + (p0 >> 1)) = od;
}

// ---------------------------------------------------------------------------
// Fused dual-parity GEMM + butterfly epilogue.
//   acc_e = Ae[mtile,:] * Re[ctile,:]^T,  acc_o = Ao * Ro^T   (K = 2048)
//   s = acc_e + acc_o -> row n;  d = acc_e - acc_o -> row 4095-n
// STAGE 1: Re/Ro = Xe/Xo; s,d written bf16 into Te/To with column
//          deinterleave (col p even -> Te[n, p>>1], odd -> To[n, p>>1]).
// STAGE 2: Re/Ro = Te/To; s,d written fp32 into out[n, w] / out[4095-n, w].
// 128x128 tile, BK=32, 4 waves x (4x4 mfma_f32_16x16x32_bf16) per parity,
// 32 MFMA per barrier pair. LDS 4 x 8KB. Grid (32,16) = 512 blocks.
// ---------------------------------------------------------------------------
template <int STAGE>
__global__ __launch_bounds__(256, 2)
void gemm_fused_kernel(const unsigned short* __restrict__ Ae,
                       const unsigned short* __restrict__ Ao,
                       const unsigned short* __restrict__ Re,
                       const unsigned short* __restrict__ Ro,
                       unsigned short* __restrict__ Te,
                       unsigned short* __restrict__ To,
                       float* __restrict__ out) {
    constexpr int KD = 2048;
    __shared__ __attribute__((aligned(16))) unsigned short lAe[128 * 32];
    __shared__ __attribute__((aligned(16))) unsigned short lAo[128 * 32];
    __shared__ __attribute__((aligned(16))) unsigned short lBe[128 * 32];
    __shared__ __attribute__((aligned(16))) unsigned short lBo[128 * 32];

    const int tid  = threadIdx.x;
    const int wave = tid >> 6;
    const int lane = tid & 63;

    const int tile_m = blockIdx.y << 7;   // rows of Ae/Ao: [0,2048)
    const int tile_c = blockIdx.x << 7;   // rows of Re/Ro (= C cols): [0,4096)

    f32x4_t acc_e[4][4], acc_o[4][4];
#pragma unroll
    for (int i = 0; i < 4; ++i)
#pragma unroll
        for (int j = 0; j < 4; ++j) {
            acc_e[i][j] = (f32x4_t){0.f, 0.f, 0.f, 0.f};
            acc_o[i][j] = (f32x4_t){0.f, 0.f, 0.f, 0.f};
        }

    // 16B-chunk scheme per 8KB buffer: 512 chunks, chunk c -> row c>>2, grp c&3
    const int c_base = wave << 6;
    const int cl0 = c_base + lane;        // 0..255
    const int cl1 = cl0 + 256;            // 256..511
    const size_t r0off = (size_t)(cl0 >> 2) * KD + ((cl0 & 3) << 3);
    const size_t r1off = (size_t)(cl1 >> 2) * KD + ((cl1 & 3) << 3);

    const unsigned short* gAe0 = Ae + (size_t)tile_m * KD + r0off;
    const unsigned short* gAe1 = Ae + (size_t)tile_m * KD + r1off;
    const unsigned short* gAo0 = Ao + (size_t)tile_m * KD + r0off;
    const unsigned short* gAo1 = Ao + (size_t)tile_m * KD + r1off;
    const unsigned short* gBe0 = Re + (size_t)tile_c * KD + r0off;
    const unsigned short* gBe1 = Re + (size_t)tile_c * KD + r1off;
    const unsigned short* gBo0 = Ro + (size_t)tile_c * KD + r0off;
    const unsigned short* gBo1 = Ro + (size_t)tile_c * KD + r1off;

    const int l0 = (c_base)       << 3;   // wave-uniform LDS chunk bases
    const int l1 = (c_base + 256) << 3;

    const int frow = lane & 15;
    const int koff = (lane >> 4) << 3;
    const int aIdx = ((wave >> 1) * 64 + frow) * 32 + koff;
    const int bIdx = ((wave & 1) * 64 + frow) * 32 + koff;

#define GLL(gp, lp) __builtin_amdgcn_global_load_lds( \
        (const __attribute__((address_space(1))) uint32_t*)(gp), \
        (__attribute__((address_space(3))) uint32_t*)(lp), 16, 0, 0)

    for (int kt = 0; kt < KD / 32; ++kt) {
        __syncthreads();
        GLL(gAe0, &lAe[l0]); GLL(gAe1, &lAe[l1]);
        GLL(gAo0, &lAo[l0]); GLL(gAo1, &lAo[l1]);
        GLL(gBe0, &lBe[l0]); GLL(gBe1, &lBe[l1]);
        GLL(gBo0, &lBo[l0]); GLL(gBo1, &lBo[l1]);
        gAe0 += 32; gAe1 += 32; gAo0 += 32; gAo1 += 32;
        gBe0 += 32; gBe1 += 32; gBo0 += 32; gBo1 += 32;
        __syncthreads();

        {
            bf16x8_t af[4], bfr[4];
#pragma unroll
            for (int i = 0; i < 4; ++i) af[i]  = *(const bf16x8_t*)(&lAe[aIdx] + i * 16 * 32);
#pragma unroll
            for (int j = 0; j < 4; ++j) bfr[j] = *(const bf16x8_t*)(&lBe[bIdx] + j * 16 * 32);
#pragma unroll
            for (int i = 0; i < 4; ++i)
#pragma unroll
                for (int j = 0; j < 4; ++j)
                    acc_e[i][j] = __builtin_amdgcn_mfma_f32_16x16x32_bf16(af[i], bfr[j], acc_e[i][j], 0, 0, 0);
        }
        {
            bf16x8_t af[4], bfr[4];
#pragma unroll
            for (int i = 0; i < 4; ++i) af[i]  = *(const bf16x8_t*)(&lAo[aIdx] + i * 16 * 32);
#pragma unroll
            for (int j = 0; j < 4; ++j) bfr[j] = *(const bf16x8_t*)(&lBo[bIdx] + j * 16 * 32);
#pragma unroll
            for (int i = 0; i < 4; ++i)
#pragma unroll
                for (int j = 0; j < 4; ++j)
                    acc_o[i][j] = __builtin_amdgcn_mfma_f32_16x16x32_bf16(af[i], bfr[j], acc_o[i][j], 0, 0, 0);
        }
    }
#undef GLL

    // C/D map: col = lane&15, row = (lane>>4)*4 + reg
    const int orow = tile_m + (wave >> 1) * 64 + ((lane >> 4) << 2);
    const int ocol = tile_c + (wave & 1) * 64 + (lane & 15);
    if (STAGE == 1) {
        // column p parity fixed per thread
        unsigned short* dst = (ocol & 1) ? To : Te;
#pragma unroll
        for (int i = 0; i < 4; ++i)
#pragma unroll
            for (int j = 0; j < 4; ++j)
#pragma unroll
                for (int r = 0; r < 4; ++r) {
                    const int n = orow + i * 16 + r;
                    const int c = (ocol + j * 16) >> 1;
                    const float e = acc_e[i][j][r], o = acc_o[i][j][r];
                    dst[(size_t)n * 2048 + c]            = (unsigned short)f32_to_bf16_bits(e + o);
                    dst[(size_t)(4095 - n) * 2048 + c]   = (unsigned short)f32_to_bf16_bits(e - o);
                }
    } else {
#pragma unroll
        for (int i = 0; i < 4; ++i)
#pragma unroll
            for (int j = 0; j < 4; ++j)
#pragma unroll
                for (int r = 0; r < 4; ++r) {
                    const int m = orow + i * 16 + r;
                    const int w = ocol + j * 16;
                    const float e = acc_e[i][j][r], o = acc_o[i][j][r];
                    out[(size_t)m * 4096 + w]          = e + o;
                    out[(size_t)(4095 - m) * 4096 + w] = e - o;
                }
    }
}

// ---------------------------------------------------------------------------
// Pipeline:
//   stage1: (Ae,Ao) x (Xe,Xo) -> butterfly -> Te,To (bf16, deinterleaved)
//   stage2: (Ae,Ao) x (Te,To) -> butterfly -> out (fp32)
// ws: Ae[0,8M) Ao[8,16M) Xe[16,32M) Xo[32,48M) Te[48,64M) To[64,80M)
// ---------------------------------------------------------------------------
extern "C" void kernel_launch(void* const* d_in, const int* in_sizes, int n_in,
                              void* d_out, int out_size, void* d_ws, size_t ws_size,
                              hipStream_t stream) {
    const float* x = (const float*)d_in[0];
    char* ws = (char*)d_ws;
    const size_t MB = 1024 * 1024;
    unsigned short* Ae = (unsigned short*)(ws);
    unsigned short* Ao = (unsigned short*)(ws + 8 * MB);
    unsigned short* Xe = (unsigned short*)(ws + 16 * MB);
    unsigned short* Xo = (unsigned short*)(ws + 32 * MB);
    unsigned short* Te = (unsigned short*)(ws + 48 * MB);
    unsigned short* To = (unsigned short*)(ws + 64 * MB);
    float* out = (float*)d_out;

    genAB_kernel<<<4096, 256, 0, stream>>>(Ae, Ao);
    cvtX_kernel<<<8192, 256, 0, stream>>>(x, Xe, Xo);

    dim3 grid(32, 16);
    gemm_fused_kernel<1><<<grid, 256, 0, stream>>>(Ae, Ao, Xe, Xo, Te, To, nullptr);
    gemm_fused_kernel<2><<<grid, 256, 0, stream>>>(Ae, Ao, Te, To, nullptr, nullptr, out);
}

// Round 4
// 293.963 us; speedup vs baseline: 1.6265x; 1.0219x over previous
//
#include <hip/hip_runtime.h>
#include <stdint.h>

typedef __bf16 bf16x8_t __attribute__((ext_vector_type(8)));
typedef float f32x4_t __attribute__((ext_vector_type(4)));

__device__ __forceinline__ uint32_t f32_to_bf16_bits(float f) {
    union { float f; uint32_t u; } v; v.f = f;
    return (v.u + 0x7FFFu + ((v.u >> 16) & 1u)) >> 16;   // RNE, finite inputs
}

// ---------------------------------------------------------------------------
// Merged prep:
//  blocks [0,4096):    Ae[n,r]=cos(pi*2r(2n+1)/8192), Ao[n,r]=cos(pi*(2r+1)(2n+1)/8192)
//  blocks [4096,12288): Xe[q,r]=bf16(x[q,2r]), Xo[q,r]=bf16(x[q,2r+1])
// ---------------------------------------------------------------------------
__global__ void prep_kernel(const float* __restrict__ X,
                            unsigned short* __restrict__ Ae,
                            unsigned short* __restrict__ Ao,
                            unsigned short* __restrict__ Xe,
                            unsigned short* __restrict__ Xo) {
    if (blockIdx.x < 4096) {
        const int idx = blockIdx.x * 256 + threadIdx.x;   // 0..1M-1
        const int sel = idx >> 19;                        // 0=even, 1=odd matrix
        const int e   = idx & ((1 << 19) - 1);
        const int n   = e >> 8;                           // 0..2047
        const int c0  = (e & 255) << 3;                   // col start
        const uint32_t tn = (uint32_t)(2 * n + 1);
        unsigned short* dst = sel ? Ao : Ae;
        uint32_t packed[4];
#pragma unroll
        for (int jj = 0; jj < 4; ++jj) {
            uint32_t cA = (uint32_t)(c0 + 2 * jj);
            uint32_t cB = cA + 1;
            uint32_t r0 = ((2u * cA + (uint32_t)sel) * tn) & 16383u;
            uint32_t r1 = ((2u * cB + (uint32_t)sel) * tn) & 16383u;
            float v0 = __cosf((float)r0 * 3.8349519697141e-4f);   // pi/8192
            float v1 = __cosf((float)r1 * 3.8349519697141e-4f);
            packed[jj] = f32_to_bf16_bits(v0) | (f32_to_bf16_bits(v1) << 16);
        }
        *(uint4*)(dst + (size_t)n * 2048 + c0) = make_uint4(packed[0], packed[1], packed[2], packed[3]);
    } else {
        const int idx = (blockIdx.x - 4096) * 256 + threadIdx.x;   // 0..2M-1
        const int q   = idx >> 9;
        const int p0  = (idx & 511) << 3;
        const float4* src = (const float4*)(X + (size_t)q * 4096 + p0);
        float4 a = src[0];
        float4 b = src[1];
        uint2 ev, od;
        ev.x = f32_to_bf16_bits(a.x) | (f32_to_bf16_bits(a.z) << 16);
        ev.y = f32_to_bf16_bits(b.x) | (f32_to_bf16_bits(b.z) << 16);
        od.x = f32_to_bf16_bits(a.y) | (f32_to_bf16_bits(a.w) << 16);
        od.y = f32_to_bf16_bits(b.y) | (f32_to_bf16_bits(b.w) << 16);
        *(uint2*)(Xe + (size_t)q * 2048 + (p0 >> 1)) = ev;
        *(uint2*)(Xo + (size_t)q * 2048 + (p0 >> 1)) = od;
    }
}

// ---------------------------------------------------------------------------
// Fused dual-parity GEMM + butterfly epilogue, BK=64.
//   acc_e = Ae[mtile,:] * Re[ctile,:]^T,  acc_o = Ao * Ro^T   (K = 2048)
//   s = acc_e + acc_o -> row n;  d = acc_e - acc_o -> row 4095-n
// STAGE 1: Re/Ro = Xe/Xo; bf16 out into Te/To with col deinterleave.
// STAGE 2: Re/Ro = Te/To; fp32 out.
// 128x128 tile, BK=64, 4 waves x (4x4x2 mfma_f32_16x16x32_bf16 per parity)
// = 64 MFMA per barrier pair per wave. LDS 4 x 16KB = 64KB. Grid 512.
// ---------------------------------------------------------------------------
template <int STAGE>
__global__ __launch_bounds__(256, 2)
void gemm_fused_kernel(const unsigned short* __restrict__ Ae,
                       const unsigned short* __restrict__ Ao,
                       const unsigned short* __restrict__ Re,
                       const unsigned short* __restrict__ Ro,
                       unsigned short* __restrict__ Te,
                       unsigned short* __restrict__ To,
                       float* __restrict__ out) {
    constexpr int KD = 2048;
    constexpr int BK = 64;
    __shared__ __attribute__((aligned(16))) unsigned short lAe[128 * BK];
    __shared__ __attribute__((aligned(16))) unsigned short lAo[128 * BK];
    __shared__ __attribute__((aligned(16))) unsigned short lBe[128 * BK];
    __shared__ __attribute__((aligned(16))) unsigned short lBo[128 * BK];

    const int tid  = threadIdx.x;
    const int wave = tid >> 6;
    const int lane = tid & 63;

    const int tile_m = blockIdx.y << 7;   // rows of Ae/Ao: [0,2048)
    const int tile_c = blockIdx.x << 7;   // rows of Re/Ro (= C cols): [0,4096)

    f32x4_t acc_e[4][4], acc_o[4][4];
#pragma unroll
    for (int i = 0; i < 4; ++i)
#pragma unroll
        for (int j = 0; j < 4; ++j) {
            acc_e[i][j] = (f32x4_t){0.f, 0.f, 0.f, 0.f};
            acc_o[i][j] = (f32x4_t){0.f, 0.f, 0.f, 0.f};
        }

    // 16B-chunk scheme per 16KB buffer: 1024 chunks; chunk c -> row c>>3,
    // 8-elem group c&7. Thread handles chunks c_base+lane (+256,+512,+768).
    const int c_base = wave << 6;
    // per-lane global row/col offsets for the 4 chunk sets
    size_t roff[4];
#pragma unroll
    for (int t = 0; t < 4; ++t) {
        const int cl = c_base + lane + 256 * t;
        roff[t] = (size_t)(cl >> 3) * KD + ((cl & 7) << 3);
    }

    const unsigned short* gAe = Ae + (size_t)tile_m * KD;
    const unsigned short* gAo = Ao + (size_t)tile_m * KD;
    const unsigned short* gBe = Re + (size_t)tile_c * KD;
    const unsigned short* gBo = Ro + (size_t)tile_c * KD;

    // wave-uniform LDS chunk-set bases (shorts); HW adds lane*16B
    int lbase[4];
#pragma unroll
    for (int t = 0; t < 4; ++t) lbase[t] = (c_base + 256 * t) << 3;

    const int frow = lane & 15;
    const int koff = (lane >> 4) << 3;
    const int aIdx = ((wave >> 1) * 64 + frow) * BK + koff;
    const int bIdx = ((wave & 1) * 64 + frow) * BK + koff;

#define GLL(gp, lp) __builtin_amdgcn_global_load_lds( \
        (const __attribute__((address_space(1))) uint32_t*)(gp), \
        (__attribute__((address_space(3))) uint32_t*)(lp), 16, 0, 0)

    for (int kt = 0; kt < KD / BK; ++kt) {
        const size_t kadv = (size_t)kt * BK;
        __syncthreads();
#pragma unroll
        for (int t = 0; t < 4; ++t) {
            GLL(gAe + kadv + roff[t], &lAe[lbase[t]]);
            GLL(gAo + kadv + roff[t], &lAo[lbase[t]]);
            GLL(gBe + kadv + roff[t], &lBe[lbase[t]]);
            GLL(gBo + kadv + roff[t], &lBo[lbase[t]]);
        }
        __syncthreads();

#pragma unroll
        for (int kh = 0; kh < 2; ++kh) {
            const int ko = kh * 32;
            {
                bf16x8_t af[4], bfr[4];
#pragma unroll
                for (int i = 0; i < 4; ++i) af[i]  = *(const bf16x8_t*)(&lAe[aIdx + ko] + i * 16 * BK);
#pragma unroll
                for (int j = 0; j < 4; ++j) bfr[j] = *(const bf16x8_t*)(&lBe[bIdx + ko] + j * 16 * BK);
#pragma unroll
                for (int i = 0; i < 4; ++i)
#pragma unroll
                    for (int j = 0; j < 4; ++j)
                        acc_e[i][j] = __builtin_amdgcn_mfma_f32_16x16x32_bf16(af[i], bfr[j], acc_e[i][j], 0, 0, 0);
            }
            {
                bf16x8_t af[4], bfr[4];
#pragma unroll
                for (int i = 0; i < 4; ++i) af[i]  = *(const bf16x8_t*)(&lAo[aIdx + ko] + i * 16 * BK);
#pragma unroll
                for (int j = 0; j < 4; ++j) bfr[j] = *(const bf16x8_t*)(&lBo[bIdx + ko] + j * 16 * BK);
#pragma unroll
                for (int i = 0; i < 4; ++i)
#pragma unroll
                    for (int j = 0; j < 4; ++j)
                        acc_o[i][j] = __builtin_amdgcn_mfma_f32_16x16x32_bf16(af[i], bfr[j], acc_o[i][j], 0, 0, 0);
            }
        }
    }
#undef GLL

    // C/D map: col = lane&15, row = (lane>>4)*4 + reg
    const int orow = tile_m + (wave >> 1) * 64 + ((lane >> 4) << 2);
    const int ocol = tile_c + (wave & 1) * 64 + (lane & 15);
    if (STAGE == 1) {
        unsigned short* dst = (ocol & 1) ? To : Te;   // parity fixed per thread
#pragma unroll
        for (int i = 0; i < 4; ++i)
#pragma unroll
            for (int j = 0; j < 4; ++j)
#pragma unroll
                for (int r = 0; r < 4; ++r) {
                    const int n = orow + i * 16 + r;
                    const int c = (ocol + j * 16) >> 1;
                    const float e = acc_e[i][j][r], o = acc_o[i][j][r];
                    dst[(size_t)n * 2048 + c]          = (unsigned short)f32_to_bf16_bits(e + o);
                    dst[(size_t)(4095 - n) * 2048 + c] = (unsigned short)f32_to_bf16_bits(e - o);
                }
    } else {
#pragma unroll
        for (int i = 0; i < 4; ++i)
#pragma unroll
            for (int j = 0; j < 4; ++j)
#pragma unroll
                for (int r = 0; r < 4; ++r) {
                    const int m = orow + i * 16 + r;
                    const int w = ocol + j * 16;
                    const float e = acc_e[i][j][r], o = acc_o[i][j][r];
                    out[(size_t)m * 4096 + w]          = e + o;
                    out[(size_t)(4095 - m) * 4096 + w] = e - o;
                }
    }
}

// ---------------------------------------------------------------------------
// Pipeline:
//   prep:   Ae,Ao (cosine tables) + Xe,Xo (deinterleaved bf16 x)
//   stage1: (Ae,Ao) x (Xe,Xo) -> butterfly -> Te,To (bf16, deinterleaved)
//   stage2: (Ae,Ao) x (Te,To) -> butterfly -> out (fp32)
// ws: Ae[0,8M) Ao[8,16M) Xe[16,32M) Xo[32,48M) Te[48,64M) To[64,80M)
// ---------------------------------------------------------------------------
extern "C" void kernel_launch(void* const* d_in, const int* in_sizes, int n_in,
                              void* d_out, int out_size, void* d_ws, size_t ws_size,
                              hipStream_t stream) {
    const float* x = (const float*)d_in[0];
    char* ws = (char*)d_ws;
    const size_t MB = 1024 * 1024;
    unsigned short* Ae = (unsigned short*)(ws);
    unsigned short* Ao = (unsigned short*)(ws + 8 * MB);
    unsigned short* Xe = (unsigned short*)(ws + 16 * MB);
    unsigned short* Xo = (unsigned short*)(ws + 32 * MB);
    unsigned short* Te = (unsigned short*)(ws + 48 * MB);
    unsigned short* To = (unsigned short*)(ws + 64 * MB);
    float* out = (float*)d_out;

    prep_kernel<<<12288, 256, 0, stream>>>(x, Ae, Ao, Xe, Xo);

    dim3 grid(32, 16);
    gemm_fused_kernel<1><<<grid, 256, 0, stream>>>(Ae, Ao, Xe, Xo, Te, To, nullptr);
    gemm_fused_kernel<2><<<grid, 256, 0, stream>>>(Ae, Ao, Te, To, nullptr, nullptr, out);
}

// Round 5
// 255.385 us; speedup vs baseline: 1.8722x; 1.1511x over previous
//
#include <hip/hip_runtime.h>
#include <stdint.h>

typedef __bf16 bf16x8_t __attribute__((ext_vector_type(8)));
typedef float f32x4_t __attribute__((ext_vector_type(4)));

__device__ __forceinline__ uint32_t f32_to_bf16_bits(float f) {
    union { float f; uint32_t u; } v; v.f = f;
    return (v.u + 0x7FFFu + ((v.u >> 16) & 1u)) >> 16;   // RNE, finite inputs
}

// ---------------------------------------------------------------------------
// Merged prep:
//  blocks [0,4096):    Ae[n,r]=cos(pi*2r(2n+1)/8192), Ao[n,r]=cos(pi*(2r+1)(2n+1)/8192)
//  blocks [4096,12288): Xe[q,r]=bf16(x[q,2r]), Xo[q,r]=bf16(x[q,2r+1])
// ---------------------------------------------------------------------------
__global__ void prep_kernel(const float* __restrict__ X,
                            unsigned short* __restrict__ Ae,
                            unsigned short* __restrict__ Ao,
                            unsigned short* __restrict__ Xe,
                            unsigned short* __restrict__ Xo) {
    if (blockIdx.x < 4096) {
        const int idx = blockIdx.x * 256 + threadIdx.x;   // 0..1M-1
        const int sel = idx >> 19;                        // 0=even, 1=odd matrix
        const int e   = idx & ((1 << 19) - 1);
        const int n   = e >> 8;                           // 0..2047
        const int c0  = (e & 255) << 3;                   // col start
        const uint32_t tn = (uint32_t)(2 * n + 1);
        unsigned short* dst = sel ? Ao : Ae;
        uint32_t packed[4];
#pragma unroll
        for (int jj = 0; jj < 4; ++jj) {
            uint32_t cA = (uint32_t)(c0 + 2 * jj);
            uint32_t cB = cA + 1;
            uint32_t r0 = ((2u * cA + (uint32_t)sel) * tn) & 16383u;
            uint32_t r1 = ((2u * cB + (uint32_t)sel) * tn) & 16383u;
            float v0 = __cosf((float)r0 * 3.8349519697141e-4f);   // pi/8192
            float v1 = __cosf((float)r1 * 3.8349519697141e-4f);
            packed[jj] = f32_to_bf16_bits(v0) | (f32_to_bf16_bits(v1) << 16);
        }
        *(uint4*)(dst + (size_t)n * 2048 + c0) = make_uint4(packed[0], packed[1], packed[2], packed[3]);
    } else {
        const int idx = (blockIdx.x - 4096) * 256 + threadIdx.x;   // 0..2M-1
        const int q   = idx >> 9;
        const int p0  = (idx & 511) << 3;
        const float4* src = (const float4*)(X + (size_t)q * 4096 + p0);
        float4 a = src[0];
        float4 b = src[1];
        uint2 ev, od;
        ev.x = f32_to_bf16_bits(a.x) | (f32_to_bf16_bits(a.z) << 16);
        ev.y = f32_to_bf16_bits(b.x) | (f32_to_bf16_bits(b.z) << 16);
        od.x = f32_to_bf16_bits(a.y) | (f32_to_bf16_bits(a.w) << 16);
        od.y = f32_to_bf16_bits(b.y) | (f32_to_bf16_bits(b.w) << 16);
        *(uint2*)(Xe + (size_t)q * 2048 + (p0 >> 1)) = ev;
        *(uint2*)(Xo + (size_t)q * 2048 + (p0 >> 1)) = od;
    }
}

// ---------------------------------------------------------------------------
// Fused dual-parity GEMM + butterfly epilogue, BK=64, XOR-swizzled LDS.
//
// LDS layout: buffer[row][slot], 8 x 16B slots per row (BK=64 bf16).
// Physical slot s of row r holds logical k-chunk g = s ^ (r & 7).
//   - staging: lane writes phys chunk (row, s) [lane-contiguous, HW scatter],
//     so it FETCHES global chunk (row, s ^ (row&7)) -- permutation within a
//     128B segment, still one coalesced transaction.
//   - reads: logical chunk g -> slot g ^ (frow&7); 8 consecutive lanes hit 8
//     distinct 4-bank slots -> conflict-free ds_read_b128.
// 128x128 tile, 4 waves x (4x4 x2 kh x2 parity mfma_f32_16x16x32_bf16).
// ---------------------------------------------------------------------------
template <int STAGE>
__global__ __launch_bounds__(256, 2)
void gemm_fused_kernel(const unsigned short* __restrict__ Ae,
                       const unsigned short* __restrict__ Ao,
                       const unsigned short* __restrict__ Re,
                       const unsigned short* __restrict__ Ro,
                       unsigned short* __restrict__ Te,
                       unsigned short* __restrict__ To,
                       float* __restrict__ out) {
    constexpr int KD = 2048;
    constexpr int BK = 64;
    __shared__ __attribute__((aligned(16))) unsigned short lAe[128 * BK];
    __shared__ __attribute__((aligned(16))) unsigned short lAo[128 * BK];
    __shared__ __attribute__((aligned(16))) unsigned short lBe[128 * BK];
    __shared__ __attribute__((aligned(16))) unsigned short lBo[128 * BK];

    const int tid  = threadIdx.x;
    const int wave = tid >> 6;
    const int lane = tid & 63;

    const int tile_m = blockIdx.y << 7;   // rows of Ae/Ao: [0,2048)
    const int tile_c = blockIdx.x << 7;   // rows of Re/Ro (= C cols): [0,4096)

    f32x4_t acc_e[4][4], acc_o[4][4];
#pragma unroll
    for (int i = 0; i < 4; ++i)
#pragma unroll
        for (int j = 0; j < 4; ++j) {
            acc_e[i][j] = (f32x4_t){0.f, 0.f, 0.f, 0.f};
            acc_o[i][j] = (f32x4_t){0.f, 0.f, 0.f, 0.f};
        }

    // Staging: 1024 chunks of 16B per buffer; phys chunk c -> row c>>3, slot c&7.
    // Global source chunk group = slot ^ (row&7)  (swizzle).
    const int c_base = wave << 6;
    size_t roff[4];
#pragma unroll
    for (int t = 0; t < 4; ++t) {
        const int cl   = c_base + lane + 256 * t;
        const int row  = cl >> 3;
        const int grp  = (cl & 7) ^ (row & 7);
        roff[t] = (size_t)row * KD + ((size_t)grp << 3);
    }

    const unsigned short* gAe = Ae + (size_t)tile_m * KD;
    const unsigned short* gAo = Ao + (size_t)tile_m * KD;
    const unsigned short* gBe = Re + (size_t)tile_c * KD;
    const unsigned short* gBo = Ro + (size_t)tile_c * KD;

    int lbase[4];
#pragma unroll
    for (int t = 0; t < 4; ++t) lbase[t] = (c_base + 256 * t) << 3;

    // Fragment read addressing (swizzled).
    const int frow = lane & 15;
    const int sw   = frow & 7;            // row&7 term; row-block strides are %8==0
    const int gq   = lane >> 4;           // base chunk group (kh adds +4)
    const int aRowB = ((wave >> 1) * 64 + frow) * BK;
    const int bRowB = ((wave & 1) * 64 + frow) * BK;

#define GLL(gp, lp) __builtin_amdgcn_global_load_lds( \
        (const __attribute__((address_space(1))) uint32_t*)(gp), \
        (__attribute__((address_space(3))) uint32_t*)(lp), 16, 0, 0)

    for (int kt = 0; kt < KD / BK; ++kt) {
        const size_t kadv = (size_t)kt * BK;
        __syncthreads();
#pragma unroll
        for (int t = 0; t < 4; ++t) {
            GLL(gAe + kadv + roff[t], &lAe[lbase[t]]);
            GLL(gAo + kadv + roff[t], &lAo[lbase[t]]);
            GLL(gBe + kadv + roff[t], &lBe[lbase[t]]);
            GLL(gBo + kadv + roff[t], &lBo[lbase[t]]);
        }
        __syncthreads();

#pragma unroll
        for (int kh = 0; kh < 2; ++kh) {
            const int slotOff = (((kh * 4 + gq) ^ sw) << 3);   // swizzled slot (shorts)
            {
                bf16x8_t af[4], bfr[4];
#pragma unroll
                for (int i = 0; i < 4; ++i) af[i]  = *(const bf16x8_t*)(&lAe[aRowB + i * 16 * BK + slotOff]);
#pragma unroll
                for (int j = 0; j < 4; ++j) bfr[j] = *(const bf16x8_t*)(&lBe[bRowB + j * 16 * BK + slotOff]);
#pragma unroll
                for (int i = 0; i < 4; ++i)
#pragma unroll
                    for (int j = 0; j < 4; ++j)
                        acc_e[i][j] = __builtin_amdgcn_mfma_f32_16x16x32_bf16(af[i], bfr[j], acc_e[i][j], 0, 0, 0);
            }
            {
                bf16x8_t af[4], bfr[4];
#pragma unroll
                for (int i = 0; i < 4; ++i) af[i]  = *(const bf16x8_t*)(&lAo[aRowB + i * 16 * BK + slotOff]);
#pragma unroll
                for (int j = 0; j < 4; ++j) bfr[j] = *(const bf16x8_t*)(&lBo[bRowB + j * 16 * BK + slotOff]);
#pragma unroll
                for (int i = 0; i < 4; ++i)
#pragma unroll
                    for (int j = 0; j < 4; ++j)
                        acc_o[i][j] = __builtin_amdgcn_mfma_f32_16x16x32_bf16(af[i], bfr[j], acc_o[i][j], 0, 0, 0);
            }
        }
    }
#undef GLL

    // C/D map: col = lane&15, row = (lane>>4)*4 + reg
    const int orow = tile_m + (wave >> 1) * 64 + ((lane >> 4) << 2);
    const int ocol = tile_c + (wave & 1) * 64 + (lane & 15);
    if (STAGE == 1) {
        unsigned short* dst = (ocol & 1) ? To : Te;   // parity fixed per thread
#pragma unroll
        for (int i = 0; i < 4; ++i)
#pragma unroll
            for (int j = 0; j < 4; ++j)
#pragma unroll
                for (int r = 0; r < 4; ++r) {
                    const int n = orow + i * 16 + r;
                    const int c = (ocol + j * 16) >> 1;
                    const float e = acc_e[i][j][r], o = acc_o[i][j][r];
                    dst[(size_t)n * 2048 + c]          = (unsigned short)f32_to_bf16_bits(e + o);
                    dst[(size_t)(4095 - n) * 2048 + c] = (unsigned short)f32_to_bf16_bits(e - o);
                }
    } else {
#pragma unroll
        for (int i = 0; i < 4; ++i)
#pragma unroll
            for (int j = 0; j < 4; ++j)
#pragma unroll
                for (int r = 0; r < 4; ++r) {
                    const int m = orow + i * 16 + r;
                    const int w = ocol + j * 16;
                    const float e = acc_e[i][j][r], o = acc_o[i][j][r];
                    out[(size_t)m * 4096 + w]          = e + o;
                    out[(size_t)(4095 - m) * 4096 + w] = e - o;
                }
    }
}

// ---------------------------------------------------------------------------
// Pipeline:
//   prep:   Ae,Ao (cosine tables) + Xe,Xo (deinterleaved bf16 x)
//   stage1: (Ae,Ao) x (Xe,Xo) -> butterfly -> Te,To (bf16, deinterleaved)
//   stage2: (Ae,Ao) x (Te,To) -> butterfly -> out (fp32)
// ws: Ae[0,8M) Ao[8,16M) Xe[16,32M) Xo[32,48M) Te[48,64M) To[64,80M)
// ---------------------------------------------------------------------------
extern "C" void kernel_launch(void* const* d_in, const int* in_sizes, int n_in,
                              void* d_out, int out_size, void* d_ws, size_t ws_size,
                              hipStream_t stream) {
    const float* x = (const float*)d_in[0];
    char* ws = (char*)d_ws;
    const size_t MB = 1024 * 1024;
    unsigned short* Ae = (unsigned short*)(ws);
    unsigned short* Ao = (unsigned short*)(ws + 8 * MB);
    unsigned short* Xe = (unsigned short*)(ws + 16 * MB);
    unsigned short* Xo = (unsigned short*)(ws + 32 * MB);
    unsigned short* Te = (unsigned short*)(ws + 48 * MB);
    unsigned short* To = (unsigned short*)(ws + 64 * MB);
    float* out = (float*)d_out;

    prep_kernel<<<12288, 256, 0, stream>>>(x, Ae, Ao, Xe, Xo);

    dim3 grid(32, 16);
    gemm_fused_kernel<1><<<grid, 256, 0, stream>>>(Ae, Ao, Xe, Xo, Te, To, nullptr);
    gemm_fused_kernel<2><<<grid, 256, 0, stream>>>(Ae, Ao, Te, To, nullptr, nullptr, out);
}